// Round 19
// baseline (224.769 us; speedup 1.0000x reference)
//
#include <hip/hip_runtime.h>

#define N_NODES 50000
#define N_EDGES 800000
#define FEA 128
#define NL 3
#define AH 512
#define NG 64
#define NBLK 196   // ceil(50000/256)

typedef short bf16x8 __attribute__((ext_vector_type(8)));
typedef float f32x4 __attribute__((ext_vector_type(4)));
typedef uint  u32x4 __attribute__((ext_vector_type(4)));

__device__ __forceinline__ ushort f2bf(float f) {   // RTN-even
    uint u = __float_as_uint(f);
    uint r = u + 0x7FFFu + ((u >> 16) & 1u);
    return (ushort)(r >> 16);
}
__device__ __forceinline__ float bf2f(ushort u) {
    return __uint_as_float((uint)u << 16);
}

// Column-sliced layouts: 4 slices of 64B (32 bf16 features) per row.
#define HS ((size_t)(N_NODES + 1) * 32)   // ushorts per H slice
#define XS ((size_t)N_NODES * 32)         // ushorts per X slice

// ---------------- mega: hist+rank (atomic-bound)  ||  gemm layer-0 (compute-bound) ----------------
#define MA 3125            // hist blocks (3125*256 = 800000 edges)
#define MB (MA + 1024)     // gemm0 blocks
#define MC (MB + 1)        // H pad-row zero
__global__ __launch_bounds__(256) void k_mega(const int* __restrict__ dst,
                                              int* __restrict__ deg,
                                              ushort* __restrict__ rank,
                                              const float* __restrict__ x,
                                              const float* __restrict__ convW0,
                                              ushort* __restrict__ H) {
    int blk = blockIdx.x;
    if (blk < MA) {                        // degree histogram + per-edge rank
        int i = blk * 256 + threadIdx.x;
        rank[i] = (ushort)atomicAdd(&deg[dst[i]], 1);
    } else if (blk < MB) {                 // gemm layer 0: A from x f32, B split in-register
        int bid = blk - MA;
        const int wv = threadIdx.x >> 6;
        const int lane = threadIdx.x & 63;
        const int lr = lane & 15;
        const int lk = lane >> 4;

        bf16x8 bhi[2][4], blo[2][4];
#pragma unroll
        for (int ct = 0; ct < 2; ++ct) {
            int col = wv * 32 + ct * 16 + lr;
#pragma unroll
            for (int kf = 0; kf < 4; ++kf) {
#pragma unroll
                for (int j = 0; j < 8; ++j) {
                    float w = convW0[(size_t)(kf * 32 + lk * 8 + j) * FEA + col];
                    ushort h = f2bf(w);
                    bhi[ct][kf][j] = (short)h;
                    blo[ct][kf][j] = (short)f2bf(w - bf2f(h));
                }
            }
        }

        for (int rt = bid; rt < N_NODES / 16; rt += 1024) {
            int r0 = rt * 16;
            const float* xrow = x + (size_t)(r0 + lr) * FEA;
            bf16x8 a[4];
#pragma unroll
            for (int kf = 0; kf < 4; ++kf) {
                float4 u0 = *(const float4*)(xrow + kf * 32 + lk * 8);
                float4 u1 = *(const float4*)(xrow + kf * 32 + lk * 8 + 4);
                a[kf][0] = (short)f2bf(u0.x); a[kf][1] = (short)f2bf(u0.y);
                a[kf][2] = (short)f2bf(u0.z); a[kf][3] = (short)f2bf(u0.w);
                a[kf][4] = (short)f2bf(u1.x); a[kf][5] = (short)f2bf(u1.y);
                a[kf][6] = (short)f2bf(u1.z); a[kf][7] = (short)f2bf(u1.w);
            }
            f32x4 acc0 = {0.f, 0.f, 0.f, 0.f};
            f32x4 acc1 = {0.f, 0.f, 0.f, 0.f};
#pragma unroll
            for (int kf = 0; kf < 4; ++kf) {
                acc0 = __builtin_amdgcn_mfma_f32_16x16x32_bf16(a[kf], bhi[0][kf], acc0, 0, 0, 0);
                acc0 = __builtin_amdgcn_mfma_f32_16x16x32_bf16(a[kf], blo[0][kf], acc0, 0, 0, 0);
                acc1 = __builtin_amdgcn_mfma_f32_16x16x32_bf16(a[kf], bhi[1][kf], acc1, 0, 0, 0);
                acc1 = __builtin_amdgcn_mfma_f32_16x16x32_bf16(a[kf], blo[1][kf], acc1, 0, 0, 0);
            }
            // store UNSCALED (dinv applied later by hscale in k_scan2)
#pragma unroll
            for (int reg = 0; reg < 4; ++reg) {
                int orow = r0 + lk * 4 + reg;
                H[(size_t)wv * HS + (size_t)orow * 32 + lr]      = f2bf(acc0[reg]);
                H[(size_t)wv * HS + (size_t)orow * 32 + 16 + lr] = f2bf(acc1[reg]);
            }
        }
    } else {                               // zero H pad rows (4 slices x 64B)
        if (threadIdx.x < 64) {
            int c = threadIdx.x >> 4, j = threadIdx.x & 15;
            ((uint*)H)[(size_t)c * (HS / 2) + (size_t)N_NODES * 16 + j] = 0;
        }
    }
}

// ---------------- scan helpers ----------------
__device__ __forceinline__ int block_scan_incl(int v, int* wsum) {
    int lane = threadIdx.x & 63, w = threadIdx.x >> 6;
    int s = v;
#pragma unroll
    for (int off = 1; off < 64; off <<= 1) {
        int t = __shfl_up(s, off);
        if (lane >= off) s += t;
    }
    if (lane == 63) wsum[w] = s;
    __syncthreads();
    int woff = 0;
    for (int k = 0; k < w; ++k) woff += wsum[k];
    return woff + s;  // block-wide inclusive
}

__global__ __launch_bounds__(256) void k_scan1(const int* __restrict__ deg,
                                               int* __restrict__ rowptr,
                                               int* __restrict__ bsum,
                                               float* __restrict__ dinv) {
    __shared__ int wsum[4];
    int i = blockIdx.x * 256 + threadIdx.x;
    int v = (i < N_NODES) ? deg[i] : 0;
    int pv = (v + 7) & ~7;                       // pad to multiple of 8
    int incl = block_scan_incl(pv, wsum);
    if (i < N_NODES) {
        rowptr[i] = incl - pv;                   // local exclusive
        dinv[i] = rsqrtf((float)v + 1.0f);
    }
    if (threadIdx.x == 255) bsum[blockIdx.x] = incl;
}

// scan2: block-sum scan (1 block)  ||  hscale: H *= dinv rowwise (3126 blocks)
#define HU4 (4 * (N_NODES + 1) * 4)   // 800016 uint4 elements in H
__global__ __launch_bounds__(256) void k_scan2(int* __restrict__ bsum,
                                               int* __restrict__ boff,
                                               int* __restrict__ rowg,
                                               const float* __restrict__ dinv,
                                               ushort* __restrict__ H) {
    if (blockIdx.x == 0) {
        __shared__ int wsum[4];
        int v = (threadIdx.x < NBLK) ? bsum[threadIdx.x] : 0;
        int incl = block_scan_incl(v, wsum);
        if (threadIdx.x < NBLK) boff[threadIdx.x] = incl - v;
        if (threadIdx.x == NBLK - 1) rowg[N_NODES] = incl;  // total padded edges
        return;
    }
    int i = (blockIdx.x - 1) * 256 + threadIdx.x;
    if (i >= HU4) return;
    int c = i / ((N_NODES + 1) * 4);
    int rem = i - c * ((N_NODES + 1) * 4);
    int row = rem >> 2;
    if (row >= N_NODES) return;                  // pad row stays zero
    float dd = dinv[row];
    u32x4 v = ((u32x4*)H)[i];
    uint w;
    w = v.x; v.x = (uint)f2bf(bf2f((ushort)w) * dd) | ((uint)f2bf(bf2f((ushort)(w >> 16)) * dd) << 16);
    w = v.y; v.y = (uint)f2bf(bf2f((ushort)w) * dd) | ((uint)f2bf(bf2f((ushort)(w >> 16)) * dd) << 16);
    w = v.z; v.z = (uint)f2bf(bf2f((ushort)w) * dd) | ((uint)f2bf(bf2f((ushort)(w >> 16)) * dd) << 16);
    w = v.w; v.w = (uint)f2bf(bf2f((ushort)w) * dd) | ((uint)f2bf(bf2f((ushort)(w >> 16)) * dd) << 16);
    ((u32x4*)H)[i] = v;
}

// ---------------- fused: CSR fill | pad slots + final rowptr (rowg) | graph bounds ----------------
#define FA 3125
#define FB (FA + NBLK)
#define FC (FB + NBLK)
__global__ __launch_bounds__(256) void k_fill2(const int* __restrict__ src,
                                               const int* __restrict__ dst,
                                               const int* __restrict__ rowptr,
                                               const int* __restrict__ boff,
                                               const ushort* __restrict__ rank,
                                               const int* __restrict__ deg,
                                               const int* __restrict__ batch,
                                               ushort* __restrict__ eidx,
                                               int* __restrict__ rowg,
                                               int* __restrict__ gstart) {
    int blk = blockIdx.x;
    if (blk < FA) {                        // CSR fill (no atomics); global base inline
        int e = blk * 256 + threadIdx.x;
        int d = dst[e];
        int base = rowptr[d] + boff[d >> 8];
        eidx[base + (int)rank[e]] = (ushort)src[e];
    } else if (blk < FB) {                 // pad slots + write final rowptr copy
        int i = (blk - FA) * 256 + threadIdx.x;
        if (i < N_NODES) {
            int d = deg[i];
            int r = rowptr[i] + boff[i >> 8];
            rowg[i] = r;
            int pd = (d + 7) & ~7;
            for (int k = d; k < pd; ++k) eidx[r + k] = (ushort)N_NODES;
        }
    } else {                               // graph bounds from sorted batch
        int i = (blk - FB) * 256 + threadIdx.x;
        if (i < N_NODES) {
            int b = batch[i];
            int bp = (i == 0) ? -1 : batch[i - 1];
            for (int g = bp + 1; g <= b; ++g) gstart[g] = i;
            if (i == N_NODES - 1)
                for (int g = b + 1; g <= NG; ++g) gstart[g] = N_NODES;
        }
    }
}

// ---------------- MFMA GEMM (layers 1,2): H'cs = dinv * (Xcs @ W), W split in-register ----------------
__global__ __launch_bounds__(256) void k_gemm(const ushort* __restrict__ X,
                                              const float* __restrict__ convWl,
                                              const float* __restrict__ dinv,
                                              ushort* __restrict__ H) {
    const int wv = threadIdx.x >> 6;
    const int lane = threadIdx.x & 63;
    const int lr = lane & 15;
    const int lk = lane >> 4;

    bf16x8 bhi[2][4], blo[2][4];
#pragma unroll
    for (int ct = 0; ct < 2; ++ct) {
        int col = wv * 32 + ct * 16 + lr;
#pragma unroll
        for (int kf = 0; kf < 4; ++kf) {
#pragma unroll
            for (int j = 0; j < 8; ++j) {
                float w = convWl[(size_t)(kf * 32 + lk * 8 + j) * FEA + col];
                ushort h = f2bf(w);
                bhi[ct][kf][j] = (short)h;
                blo[ct][kf][j] = (short)f2bf(w - bf2f(h));
            }
        }
    }

    for (int rt = blockIdx.x; rt < N_NODES / 16; rt += gridDim.x) {
        int r0 = rt * 16;
        bf16x8 a[4];
#pragma unroll
        for (int kf = 0; kf < 4; ++kf) {
            a[kf] = *(const bf16x8*)(X + (size_t)kf * XS + (size_t)(r0 + lr) * 32 + lk * 8);
        }
        f32x4 acc0 = {0.f, 0.f, 0.f, 0.f};
        f32x4 acc1 = {0.f, 0.f, 0.f, 0.f};
#pragma unroll
        for (int kf = 0; kf < 4; ++kf) {
            acc0 = __builtin_amdgcn_mfma_f32_16x16x32_bf16(a[kf], bhi[0][kf], acc0, 0, 0, 0);
            acc0 = __builtin_amdgcn_mfma_f32_16x16x32_bf16(a[kf], blo[0][kf], acc0, 0, 0, 0);
            acc1 = __builtin_amdgcn_mfma_f32_16x16x32_bf16(a[kf], bhi[1][kf], acc1, 0, 0, 0);
            acc1 = __builtin_amdgcn_mfma_f32_16x16x32_bf16(a[kf], blo[1][kf], acc1, 0, 0, 0);
        }
#pragma unroll
        for (int reg = 0; reg < 4; ++reg) {
            int orow = r0 + lk * 4 + reg;
            float s = dinv[orow];
            H[(size_t)wv * HS + (size_t)orow * 32 + lr]      = f2bf(acc0[reg] * s);
            H[(size_t)wv * HS + (size_t)orow * 32 + 16 + lr] = f2bf(acc1[reg] * s);
        }
    }
}

// ---------------- gather: 4 lanes/node x one 64B slice; 16-edge MLP batches ----------------
#define GNPB 64    // nodes per block
#define GNB ((N_NODES + GNPB - 1) / GNPB)
__global__ __launch_bounds__(256) void k_gather(const int* __restrict__ rowg,
                                                const ushort* __restrict__ eidx,
                                                const float* __restrict__ dinv,
                                                const ushort* __restrict__ H,
                                                const float* __restrict__ b,
                                                ushort* __restrict__ X) {
    int c = blockIdx.x & 3;
    int node = (blockIdx.x >> 2) * GNPB + (threadIdx.x >> 2);
    int l4 = threadIdx.x & 3;              // uint4 offset within 64B slice row
    if (node >= N_NODES) return;
    const uint4* Hs = (const uint4*)H + (size_t)c * (N_NODES + 1) * 4;
    int r0 = rowg[node], r1 = rowg[node + 1];

    float a[8] = {0.f, 0.f, 0.f, 0.f, 0.f, 0.f, 0.f, 0.f};
#define ACC8(u)                                                              \
    do {                                                                     \
        a[0] += __uint_as_float((u).x << 16);                                \
        a[1] += __uint_as_float((u).x & 0xffff0000u);                        \
        a[2] += __uint_as_float((u).y << 16);                                \
        a[3] += __uint_as_float((u).y & 0xffff0000u);                        \
        a[4] += __uint_as_float((u).z << 16);                                \
        a[5] += __uint_as_float((u).z & 0xffff0000u);                        \
        a[6] += __uint_as_float((u).w << 16);                                \
        a[7] += __uint_as_float((u).w & 0xffff0000u);                        \
    } while (0)

    uint4 sv = Hs[(size_t)node * 4 + l4];  // self term
    ACC8(sv);

    int j = r0;
    for (; j + 16 <= r1; j += 16) {        // 16 independent H-row loads in flight
        uint4 ev0 = *(const uint4*)(eidx + j);
        uint4 ev1 = *(const uint4*)(eidx + j + 8);
        uint4 h0 = Hs[(size_t)(ev0.x & 0xffff) * 4 + l4];
        uint4 h1 = Hs[(size_t)(ev0.x >> 16) * 4 + l4];
        uint4 h2 = Hs[(size_t)(ev0.y & 0xffff) * 4 + l4];
        uint4 h3 = Hs[(size_t)(ev0.y >> 16) * 4 + l4];
        uint4 h4 = Hs[(size_t)(ev0.z & 0xffff) * 4 + l4];
        uint4 h5 = Hs[(size_t)(ev0.z >> 16) * 4 + l4];
        uint4 h6 = Hs[(size_t)(ev0.w & 0xffff) * 4 + l4];
        uint4 h7 = Hs[(size_t)(ev0.w >> 16) * 4 + l4];
        uint4 g0 = Hs[(size_t)(ev1.x & 0xffff) * 4 + l4];
        uint4 g1 = Hs[(size_t)(ev1.x >> 16) * 4 + l4];
        uint4 g2 = Hs[(size_t)(ev1.y & 0xffff) * 4 + l4];
        uint4 g3 = Hs[(size_t)(ev1.y >> 16) * 4 + l4];
        uint4 g4 = Hs[(size_t)(ev1.z & 0xffff) * 4 + l4];
        uint4 g5 = Hs[(size_t)(ev1.z >> 16) * 4 + l4];
        uint4 g6 = Hs[(size_t)(ev1.w & 0xffff) * 4 + l4];
        uint4 g7 = Hs[(size_t)(ev1.w >> 16) * 4 + l4];
        ACC8(h0); ACC8(h1); ACC8(h2); ACC8(h3);
        ACC8(h4); ACC8(h5); ACC8(h6); ACC8(h7);
        ACC8(g0); ACC8(g1); ACC8(g2); ACC8(g3);
        ACC8(g4); ACC8(g5); ACC8(g6); ACC8(g7);
    }
    if (j < r1) {                          // 8-edge tail
        uint4 ev = *(const uint4*)(eidx + j);
        uint4 h0 = Hs[(size_t)(ev.x & 0xffff) * 4 + l4];
        uint4 h1 = Hs[(size_t)(ev.x >> 16) * 4 + l4];
        uint4 h2 = Hs[(size_t)(ev.y & 0xffff) * 4 + l4];
        uint4 h3 = Hs[(size_t)(ev.y >> 16) * 4 + l4];
        uint4 h4 = Hs[(size_t)(ev.z & 0xffff) * 4 + l4];
        uint4 h5 = Hs[(size_t)(ev.z >> 16) * 4 + l4];
        uint4 h6 = Hs[(size_t)(ev.w & 0xffff) * 4 + l4];
        uint4 h7 = Hs[(size_t)(ev.w >> 16) * 4 + l4];
        ACC8(h0); ACC8(h1); ACC8(h2); ACC8(h3);
        ACC8(h4); ACC8(h5); ACC8(h6); ACC8(h7);
    }
#undef ACC8

    float di = dinv[node];
    const float4* b4 = (const float4*)(b + c * 32 + l4 * 8);
    float4 bb0 = b4[0], bb1 = b4[1];
    float o[8];
    o[0] = fmaxf(a[0] * di + bb0.x, 0.f);
    o[1] = fmaxf(a[1] * di + bb0.y, 0.f);
    o[2] = fmaxf(a[2] * di + bb0.z, 0.f);
    o[3] = fmaxf(a[3] * di + bb0.w, 0.f);
    o[4] = fmaxf(a[4] * di + bb1.x, 0.f);
    o[5] = fmaxf(a[5] * di + bb1.y, 0.f);
    o[6] = fmaxf(a[6] * di + bb1.z, 0.f);
    o[7] = fmaxf(a[7] * di + bb1.w, 0.f);

    ushort hs[8];
#pragma unroll
    for (int i = 0; i < 8; ++i) hs[i] = f2bf(o[i]);
    u32x4 hv;
    hv.x = (uint)hs[0] | ((uint)hs[1] << 16);
    hv.y = (uint)hs[2] | ((uint)hs[3] << 16);
    hv.z = (uint)hs[4] | ((uint)hs[5] << 16);
    hv.w = (uint)hs[6] | ((uint)hs[7] << 16);
    __builtin_nontemporal_store(hv, (u32x4*)(X + (size_t)c * XS + (size_t)node * 32 + l4 * 8));
}

// ---------------- pool + node head (no atomics), 16 partials/graph ----------------
__global__ __launch_bounds__(256) void k_pool(const ushort* __restrict__ X,
                                              const int* __restrict__ gstart,
                                              const float* __restrict__ nw,
                                              const float* __restrict__ nbp,
                                              float* __restrict__ out_node,
                                              float* __restrict__ psum_part) {
    int g = blockIdx.x >> 4, p = blockIdx.x & 15;
    int s = gstart[g], e = gstart[g + 1];
    int len = e - s;
    int lp = (len + 15) >> 4;
    int ps = s + p * lp, pe = min(ps + lp, e);
    int q = threadIdx.x >> 6, lane = threadIdx.x & 63;
    const uint* hb = (const uint*)X + (size_t)(lane >> 4) * (XS / 2) + (lane & 15);
    float2 w = ((const float2*)nw)[lane];
    float nbv = nbp[0];
    float2 acc = {0.f, 0.f};
    for (int node = ps + q; node < pe; node += 4) {
        uint hv = hb[(size_t)node * 16];
        float2 v;
        v.x = bf2f((ushort)hv);
        v.y = bf2f((ushort)(hv >> 16));
        acc.x += v.x; acc.y += v.y;
        float dot = v.x * w.x + v.y * w.y;
#pragma unroll
        for (int off = 32; off; off >>= 1) dot += __shfl_down(dot, off);
        if (lane == 0) out_node[node] = dot + nbv;
    }
    __shared__ float lds[4 * FEA];
    lds[q * FEA + lane * 2 + 0] = acc.x;
    lds[q * FEA + lane * 2 + 1] = acc.y;
    __syncthreads();
    if (threadIdx.x < FEA) {
        psum_part[(size_t)blockIdx.x * FEA + threadIdx.x] =
            lds[threadIdx.x] + lds[FEA + threadIdx.x] +
            lds[2 * FEA + threadIdx.x] + lds[3 * FEA + threadIdx.x];
    }
}

// ---------------- MLP layer 1 (direct strided w1 reads) ----------------
__global__ __launch_bounds__(256) void k_mlp1(const float* __restrict__ psum_part,
                                              const int* __restrict__ gstart,
                                              const float* __restrict__ w1,
                                              const float* __restrict__ b1,
                                              float* __restrict__ h1ws) {
    __shared__ float feas[NG * 132];   // pad 132 to spread banks
    for (int idx = threadIdx.x; idx < NG * FEA; idx += 256) {
        int g = idx >> 7, f = idx & 127;
        const float* pp = psum_part + (size_t)g * 16 * FEA + f;
        float sum = 0.f;
#pragma unroll
        for (int p = 0; p < 16; ++p) sum += pp[p * FEA];
        float cnt = fmaxf((float)(gstart[g + 1] - gstart[g]), 1.0f);
        feas[g * 132 + f] = sum / cnt;
    }
    __syncthreads();
    int g = threadIdx.x >> 2, jj = threadIdx.x & 3;
    int j = blockIdx.x * 4 + jj;
    const float* fr = feas + g * 132;
    float a0 = 0.f, a1 = 0.f, a2 = 0.f, a3 = 0.f;
#pragma unroll 8
    for (int k = 0; k < FEA; k += 4) {
        a0 += fr[k + 0] * w1[(k + 0) * AH + j];
        a1 += fr[k + 1] * w1[(k + 1) * AH + j];
        a2 += fr[k + 2] * w1[(k + 2) * AH + j];
        a3 += fr[k + 3] * w1[(k + 3) * AH + j];
    }
    h1ws[(size_t)g * AH + j] = fmaxf((a0 + a1) + (a2 + a3) + b1[j], 0.f);
}

// ---------------- MLP layer 2 (direct strided w2 reads) ----------------
__global__ __launch_bounds__(256) void k_mlp2(const float* __restrict__ h1ws,
                                              const float* __restrict__ w2,
                                              const float* __restrict__ b2,
                                              float* __restrict__ out_fea) {
    int f = blockIdx.x;
    int g = threadIdx.x >> 2, q = threadIdx.x & 3;
    const float* hr = h1ws + (size_t)g * AH + q * 128;
    const float* wr = w2 + (size_t)q * 128 * FEA + f;
    float a0 = 0.f, a1 = 0.f, a2 = 0.f, a3 = 0.f;
#pragma unroll 8
    for (int k = 0; k < 128; k += 4) {
        a0 += hr[k + 0] * wr[(k + 0) * FEA];
        a1 += hr[k + 1] * wr[(k + 1) * FEA];
        a2 += hr[k + 2] * wr[(k + 2) * FEA];
        a3 += hr[k + 3] * wr[(k + 3) * FEA];
    }
    float p = (a0 + a1) + (a2 + a3);
    p += __shfl_xor(p, 1);
    p += __shfl_xor(p, 2);
    if (q == 0) out_fea[(size_t)g * FEA + f] = p + b2[f];
}

extern "C" void kernel_launch(void* const* d_in, const int* in_sizes, int n_in,
                              void* d_out, int out_size, void* d_ws, size_t ws_size,
                              hipStream_t stream) {
    const float* x     = (const float*)d_in[0];
    const int*   ei    = (const int*)d_in[1];
    const int*   batch = (const int*)d_in[2];
    const float* convW = (const float*)d_in[3];
    const float* convb = (const float*)d_in[4];
    const float* w1    = (const float*)d_in[5];
    const float* b1    = (const float*)d_in[6];
    const float* w2    = (const float*)d_in[7];
    const float* b2    = (const float*)d_in[8];
    const float* nw    = (const float*)d_in[9];
    const float* nb    = (const float*)d_in[10];
    float* out = (float*)d_out;

    // workspace layout (4-byte word offsets)
    char* wsb = (char*)d_ws;
    int*    deg    = (int*)wsb;                        // 50000
    float*  dinv   = (float*)(wsb + 50048ll * 4);      // 50000
    int*    rowptr = (int*)(wsb + 100096ll * 4);       // 50001 (local)
    int*    rowg   = (int*)(wsb + 150160ll * 4);       // 50001 (global/final)
    int*    bsum   = (int*)(wsb + 200224ll * 4);       // 196
    int*    boff   = (int*)(wsb + 200424ll * 4);       // 196
    int*    gstart = (int*)(wsb + 200624ll * 4);       // 65
    int*    rankw  = (int*)(wsb + 200704ll * 4);       // 400000 words
    ushort* rank   = (ushort*)rankw;                   // 800000 ushort
    float*  h1ws   = (float*)rankw;                    // 32768 w (after fill)
    ushort* eidx   = (ushort*)(wsb + 950656ll * 4);    // <=1.3M ushort
    ushort* H      = (ushort*)(wsb + 1600672ll * 4);   // 4*(N+1)*32 bf16
    ushort* X      = (ushort*)(wsb + 4800736ll * 4);   // 4*N*32 bf16
    float*  psum_part = (float*)(wsb + 8000736ll * 4); // 1024*128 floats

    const int* srcp = ei;
    const int* dstp = ei + N_EDGES;

    // ---- CSR build overlapped with gemm layer 0 ----
    hipMemsetAsync(deg, 0, N_NODES * sizeof(int), stream);
    k_mega<<<MC, 256, 0, stream>>>(dstp, deg, rank, x, convW, H);
    k_scan1<<<NBLK, 256, 0, stream>>>(deg, rowptr, bsum, dinv);
    k_scan2<<<1 + (HU4 + 255) / 256, 256, 0, stream>>>(bsum, boff, rowg, dinv, H);
    k_fill2<<<FC, 256, 0, stream>>>(srcp, dstp, rowptr, boff, rank, deg, batch,
                                    eidx, rowg, gstart);

    // ---- GCN layers ----
    k_gather<<<GNB * 4, 256, 0, stream>>>(rowg, eidx, dinv, H, convb, X);
    for (int l = 1; l < NL; ++l) {
        k_gemm<<<1024, 256, 0, stream>>>(X, convW + (size_t)l * FEA * FEA, dinv, H);
        k_gather<<<GNB * 4, 256, 0, stream>>>(
            rowg, eidx, dinv, H, convb + (size_t)l * FEA, X);
    }

    // ---- heads ----
    k_pool<<<NG * 16, 256, 0, stream>>>(X, gstart, nw, nb, out, psum_part);
    k_mlp1<<<128, 256, 0, stream>>>(psum_part, gstart, w1, b1, h1ws);
    k_mlp2<<<128, 256, 0, stream>>>(h1ws, w2, b2, out + N_NODES);
}

// Round 20
// 220.086 us; speedup vs baseline: 1.0213x; 1.0213x over previous
//
#include <hip/hip_runtime.h>

#define N_NODES 50000
#define N_EDGES 800000
#define FEA 128
#define NL 3
#define AH 512
#define NG 64
#define NBLK 196   // ceil(50000/256)

typedef short bf16x8 __attribute__((ext_vector_type(8)));
typedef float f32x4 __attribute__((ext_vector_type(4)));
typedef uint  u32x4 __attribute__((ext_vector_type(4)));

__device__ __forceinline__ ushort f2bf(float f) {   // RTN-even
    uint u = __float_as_uint(f);
    uint r = u + 0x7FFFu + ((u >> 16) & 1u);
    return (ushort)(r >> 16);
}
__device__ __forceinline__ float bf2f(ushort u) {
    return __uint_as_float((uint)u << 16);
}

// Column-sliced layouts: 4 slices of 64B (32 bf16 features) per row.
#define HS ((size_t)(N_NODES + 1) * 32)   // ushorts per H slice
#define XS ((size_t)N_NODES * 32)   // ushorts per X slice

// ---------------- mega: interleaved hist+rank || gemm0 (col-half blocks) ----------------
// period-5 role map: 3 hist + 2 gemm -> both run concurrently from t=0.
#define NPER 1042
#define MGRID (NPER * 5 + 1)   // + pad-row block
__global__ __launch_bounds__(256) void k_mega(const int* __restrict__ dst,
                                              int* __restrict__ deg,
                                              ushort* __restrict__ rank,
                                              const float* __restrict__ x,
                                              const float* __restrict__ convW0,
                                              ushort* __restrict__ H) {
    int blk = blockIdx.x;
    if (blk == MGRID - 1) {                // zero H pad rows (4 slices x 64B)
        if (threadIdx.x < 64) {
            int c = threadIdx.x >> 4, j = threadIdx.x & 15;
            ((uint*)H)[(size_t)c * (HS / 2) + (size_t)N_NODES * 16 + j] = 0;
        }
        return;
    }
    int p = blk / 5, r = blk - p * 5;
    if (r < 3) {                           // histogram role
        int hid = p * 3 + r;
        if (hid >= 3125) return;
        int i = hid * 256 + threadIdx.x;
        rank[i] = (ushort)atomicAdd(&deg[dst[i]], 1);
        return;
    }
    // gemm0 role: col-half gid, 1 col-tile (16 cols) per wave
    int gid = p * 2 + (r - 3);
    if (gid >= 2048) return;
    const int colhalf = gid & 1;
    const int rstart = gid >> 1;           // 0..1023
    const int wv = threadIdx.x >> 6;
    const int lane = threadIdx.x & 63;
    const int lr = lane & 15;
    const int lk = lane >> 4;

    const int col = colhalf * 64 + wv * 16 + lr;
    bf16x8 bhi[4], blo[4];
#pragma unroll
    for (int kf = 0; kf < 4; ++kf) {
#pragma unroll
        for (int j = 0; j < 8; ++j) {
            float w = convW0[(size_t)(kf * 32 + lk * 8 + j) * FEA + col];
            ushort h = f2bf(w);
            bhi[kf][j] = (short)h;
            blo[kf][j] = (short)f2bf(w - bf2f(h));
        }
    }
    const int slice = colhalf * 2 + (wv >> 1);
    const int intra = (wv & 1) * 16 + lr;

    for (int rt = rstart; rt < N_NODES / 16; rt += 1024) {
        int r0 = rt * 16;
        const float* xrow = x + (size_t)(r0 + lr) * FEA;
        bf16x8 a[4];
#pragma unroll
        for (int kf = 0; kf < 4; ++kf) {
            float4 u0 = *(const float4*)(xrow + kf * 32 + lk * 8);
            float4 u1 = *(const float4*)(xrow + kf * 32 + lk * 8 + 4);
            a[kf][0] = (short)f2bf(u0.x); a[kf][1] = (short)f2bf(u0.y);
            a[kf][2] = (short)f2bf(u0.z); a[kf][3] = (short)f2bf(u0.w);
            a[kf][4] = (short)f2bf(u1.x); a[kf][5] = (short)f2bf(u1.y);
            a[kf][6] = (short)f2bf(u1.z); a[kf][7] = (short)f2bf(u1.w);
        }
        f32x4 acc = {0.f, 0.f, 0.f, 0.f};
#pragma unroll
        for (int kf = 0; kf < 4; ++kf) {
            acc = __builtin_amdgcn_mfma_f32_16x16x32_bf16(a[kf], bhi[kf], acc, 0, 0, 0);
            acc = __builtin_amdgcn_mfma_f32_16x16x32_bf16(a[kf], blo[kf], acc, 0, 0, 0);
        }
        // store UNSCALED (dinv applied later by hscale in k_scan2)
#pragma unroll
        for (int reg = 0; reg < 4; ++reg) {
            int orow = r0 + lk * 4 + reg;
            H[(size_t)slice * HS + (size_t)orow * 32 + intra] = f2bf(acc[reg]);
        }
    }
}

// ---------------- scan helpers ----------------
__device__ __forceinline__ int block_scan_incl(int v, int* wsum) {
    int lane = threadIdx.x & 63, w = threadIdx.x >> 6;
    int s = v;
#pragma unroll
    for (int off = 1; off < 64; off <<= 1) {
        int t = __shfl_up(s, off);
        if (lane >= off) s += t;
    }
    if (lane == 63) wsum[w] = s;
    __syncthreads();
    int woff = 0;
    for (int k = 0; k < w; ++k) woff += wsum[k];
    return woff + s;  // block-wide inclusive
}

__global__ __launch_bounds__(256) void k_scan1(const int* __restrict__ deg,
                                               int* __restrict__ rowptr,
                                               int* __restrict__ bsum,
                                               float* __restrict__ dinv) {
    __shared__ int wsum[4];
    int i = blockIdx.x * 256 + threadIdx.x;
    int v = (i < N_NODES) ? deg[i] : 0;
    int pv = (v + 7) & ~7;                       // pad to multiple of 8
    int incl = block_scan_incl(pv, wsum);
    if (i < N_NODES) {
        rowptr[i] = incl - pv;                   // local exclusive
        dinv[i] = rsqrtf((float)v + 1.0f);
    }
    if (threadIdx.x == 255) bsum[blockIdx.x] = incl;
}

// scan2: block-sum scan (1 block)  ||  hscale: H *= dinv rowwise (3126 blocks)
#define HU4 (4 * (N_NODES + 1) * 4)   // 800016 uint4 elements in H
__global__ __launch_bounds__(256) void k_scan2(int* __restrict__ bsum,
                                               int* __restrict__ boff,
                                               int* __restrict__ rowg,
                                               const float* __restrict__ dinv,
                                               ushort* __restrict__ H) {
    if (blockIdx.x == 0) {
        __shared__ int wsum[4];
        int v = (threadIdx.x < NBLK) ? bsum[threadIdx.x] : 0;
        int incl = block_scan_incl(v, wsum);
        if (threadIdx.x < NBLK) boff[threadIdx.x] = incl - v;
        if (threadIdx.x == NBLK - 1) rowg[N_NODES] = incl;  // total padded edges
        return;
    }
    int i = (blockIdx.x - 1) * 256 + threadIdx.x;
    if (i >= HU4) return;
    int c = i / ((N_NODES + 1) * 4);
    int rem = i - c * ((N_NODES + 1) * 4);
    int row = rem >> 2;
    if (row >= N_NODES) return;                  // pad row stays zero
    float dd = dinv[row];
    u32x4 v = ((u32x4*)H)[i];
    uint w;
    w = v.x; v.x = (uint)f2bf(bf2f((ushort)w) * dd) | ((uint)f2bf(bf2f((ushort)(w >> 16)) * dd) << 16);
    w = v.y; v.y = (uint)f2bf(bf2f((ushort)w) * dd) | ((uint)f2bf(bf2f((ushort)(w >> 16)) * dd) << 16);
    w = v.z; v.z = (uint)f2bf(bf2f((ushort)w) * dd) | ((uint)f2bf(bf2f((ushort)(w >> 16)) * dd) << 16);
    w = v.w; v.w = (uint)f2bf(bf2f((ushort)w) * dd) | ((uint)f2bf(bf2f((ushort)(w >> 16)) * dd) << 16);
    ((u32x4*)H)[i] = v;
}

// ---------------- fused: CSR fill | pad slots + final rowptr (rowg) | graph bounds ----------------
#define FA 3125
#define FB (FA + NBLK)
#define FC (FB + NBLK)
__global__ __launch_bounds__(256) void k_fill2(const int* __restrict__ src,
                                               const int* __restrict__ dst,
                                               const int* __restrict__ rowptr,
                                               const int* __restrict__ boff,
                                               const ushort* __restrict__ rank,
                                               const int* __restrict__ deg,
                                               const int* __restrict__ batch,
                                               ushort* __restrict__ eidx,
                                               int* __restrict__ rowg,
                                               int* __restrict__ gstart) {
    int blk = blockIdx.x;
    if (blk < FA) {                        // CSR fill (no atomics); global base inline
        int e = blk * 256 + threadIdx.x;
        int d = dst[e];
        int base = rowptr[d] + boff[d >> 8];
        eidx[base + (int)rank[e]] = (ushort)src[e];
    } else if (blk < FB) {                 // pad slots + write final rowptr copy
        int i = (blk - FA) * 256 + threadIdx.x;
        if (i < N_NODES) {
            int d = deg[i];
            int r = rowptr[i] + boff[i >> 8];
            rowg[i] = r;
            int pd = (d + 7) & ~7;
            for (int k = d; k < pd; ++k) eidx[r + k] = (ushort)N_NODES;
        }
    } else {                               // graph bounds from sorted batch
        int i = (blk - FB) * 256 + threadIdx.x;
        if (i < N_NODES) {
            int b = batch[i];
            int bp = (i == 0) ? -1 : batch[i - 1];
            for (int g = bp + 1; g <= b; ++g) gstart[g] = i;
            if (i == N_NODES - 1)
                for (int g = b + 1; g <= NG; ++g) gstart[g] = N_NODES;
        }
    }
}

// ---------------- MFMA GEMM (layers 1,2): H'cs = dinv * (Xcs @ W), W split in-register ----------------
__global__ __launch_bounds__(256) void k_gemm(const ushort* __restrict__ X,
                                              const float* __restrict__ convWl,
                                              const float* __restrict__ dinv,
                                              ushort* __restrict__ H) {
    const int wv = threadIdx.x >> 6;
    const int lane = threadIdx.x & 63;
    const int lr = lane & 15;
    const int lk = lane >> 4;

    bf16x8 bhi[2][4], blo[2][4];
#pragma unroll
    for (int ct = 0; ct < 2; ++ct) {
        int col = wv * 32 + ct * 16 + lr;
#pragma unroll
        for (int kf = 0; kf < 4; ++kf) {
#pragma unroll
            for (int j = 0; j < 8; ++j) {
                float w = convWl[(size_t)(kf * 32 + lk * 8 + j) * FEA + col];
                ushort h = f2bf(w);
                bhi[ct][kf][j] = (short)h;
                blo[ct][kf][j] = (short)f2bf(w - bf2f(h));
            }
        }
    }

    for (int rt = blockIdx.x; rt < N_NODES / 16; rt += gridDim.x) {
        int r0 = rt * 16;
        bf16x8 a[4];
#pragma unroll
        for (int kf = 0; kf < 4; ++kf) {
            a[kf] = *(const bf16x8*)(X + (size_t)kf * XS + (size_t)(r0 + lr) * 32 + lk * 8);
        }
        f32x4 acc0 = {0.f, 0.f, 0.f, 0.f};
        f32x4 acc1 = {0.f, 0.f, 0.f, 0.f};
#pragma unroll
        for (int kf = 0; kf < 4; ++kf) {
            acc0 = __builtin_amdgcn_mfma_f32_16x16x32_bf16(a[kf], bhi[0][kf], acc0, 0, 0, 0);
            acc0 = __builtin_amdgcn_mfma_f32_16x16x32_bf16(a[kf], blo[0][kf], acc0, 0, 0, 0);
            acc1 = __builtin_amdgcn_mfma_f32_16x16x32_bf16(a[kf], bhi[1][kf], acc1, 0, 0, 0);
            acc1 = __builtin_amdgcn_mfma_f32_16x16x32_bf16(a[kf], blo[1][kf], acc1, 0, 0, 0);
        }
#pragma unroll
        for (int reg = 0; reg < 4; ++reg) {
            int orow = r0 + lk * 4 + reg;
            float s = dinv[orow];
            H[(size_t)wv * HS + (size_t)orow * 32 + lr]      = f2bf(acc0[reg] * s);
            H[(size_t)wv * HS + (size_t)orow * 32 + 16 + lr] = f2bf(acc1[reg] * s);
        }
    }
}

// ---------------- gather: 4 lanes/node x one 64B slice; 16-edge MLP batches ----------------
#define GNPB 64    // nodes per block
#define GNB ((N_NODES + GNPB - 1) / GNPB)
__global__ __launch_bounds__(256) void k_gather(const int* __restrict__ rowg,
                                                const ushort* __restrict__ eidx,
                                                const float* __restrict__ dinv,
                                                const ushort* __restrict__ H,
                                                const float* __restrict__ b,
                                                ushort* __restrict__ X) {
    int c = blockIdx.x & 3;
    int node = (blockIdx.x >> 2) * GNPB + (threadIdx.x >> 2);
    int l4 = threadIdx.x & 3;              // uint4 offset within 64B slice row
    if (node >= N_NODES) return;
    const uint4* Hs = (const uint4*)H + (size_t)c * (N_NODES + 1) * 4;
    int r0 = rowg[node], r1 = rowg[node + 1];

    float a[8] = {0.f, 0.f, 0.f, 0.f, 0.f, 0.f, 0.f, 0.f};
#define ACC8(u)                                                              \
    do {                                                                     \
        a[0] += __uint_as_float((u).x << 16);                                \
        a[1] += __uint_as_float((u).x & 0xffff0000u);                        \
        a[2] += __uint_as_float((u).y << 16);                                \
        a[3] += __uint_as_float((u).y & 0xffff0000u);                        \
        a[4] += __uint_as_float((u).z << 16);                                \
        a[5] += __uint_as_float((u).z & 0xffff0000u);                        \
        a[6] += __uint_as_float((u).w << 16);                                \
        a[7] += __uint_as_float((u).w & 0xffff0000u);                        \
    } while (0)

    uint4 sv = Hs[(size_t)node * 4 + l4];  // self term
    ACC8(sv);

    int j = r0;
    for (; j + 16 <= r1; j += 16) {        // 16 independent H-row loads in flight
        uint4 ev0 = *(const uint4*)(eidx + j);
        uint4 ev1 = *(const uint4*)(eidx + j + 8);
        uint4 h0 = Hs[(size_t)(ev0.x & 0xffff) * 4 + l4];
        uint4 h1 = Hs[(size_t)(ev0.x >> 16) * 4 + l4];
        uint4 h2 = Hs[(size_t)(ev0.y & 0xffff) * 4 + l4];
        uint4 h3 = Hs[(size_t)(ev0.y >> 16) * 4 + l4];
        uint4 h4 = Hs[(size_t)(ev0.z & 0xffff) * 4 + l4];
        uint4 h5 = Hs[(size_t)(ev0.z >> 16) * 4 + l4];
        uint4 h6 = Hs[(size_t)(ev0.w & 0xffff) * 4 + l4];
        uint4 h7 = Hs[(size_t)(ev0.w >> 16) * 4 + l4];
        uint4 g0 = Hs[(size_t)(ev1.x & 0xffff) * 4 + l4];
        uint4 g1 = Hs[(size_t)(ev1.x >> 16) * 4 + l4];
        uint4 g2 = Hs[(size_t)(ev1.y & 0xffff) * 4 + l4];
        uint4 g3 = Hs[(size_t)(ev1.y >> 16) * 4 + l4];
        uint4 g4 = Hs[(size_t)(ev1.z & 0xffff) * 4 + l4];
        uint4 g5 = Hs[(size_t)(ev1.z >> 16) * 4 + l4];
        uint4 g6 = Hs[(size_t)(ev1.w & 0xffff) * 4 + l4];
        uint4 g7 = Hs[(size_t)(ev1.w >> 16) * 4 + l4];
        ACC8(h0); ACC8(h1); ACC8(h2); ACC8(h3);
        ACC8(h4); ACC8(h5); ACC8(h6); ACC8(h7);
        ACC8(g0); ACC8(g1); ACC8(g2); ACC8(g3);
        ACC8(g4); ACC8(g5); ACC8(g6); ACC8(g7);
    }
    if (j < r1) {                          // 8-edge tail
        uint4 ev = *(const uint4*)(eidx + j);
        uint4 h0 = Hs[(size_t)(ev.x & 0xffff) * 4 + l4];
        uint4 h1 = Hs[(size_t)(ev.x >> 16) * 4 + l4];
        uint4 h2 = Hs[(size_t)(ev.y & 0xffff) * 4 + l4];
        uint4 h3 = Hs[(size_t)(ev.y >> 16) * 4 + l4];
        uint4 h4 = Hs[(size_t)(ev.z & 0xffff) * 4 + l4];
        uint4 h5 = Hs[(size_t)(ev.z >> 16) * 4 + l4];
        uint4 h6 = Hs[(size_t)(ev.w & 0xffff) * 4 + l4];
        uint4 h7 = Hs[(size_t)(ev.w >> 16) * 4 + l4];
        ACC8(h0); ACC8(h1); ACC8(h2); ACC8(h3);
        ACC8(h4); ACC8(h5); ACC8(h6); ACC8(h7);
    }
#undef ACC8

    float di = dinv[node];
    const float4* b4 = (const float4*)(b + c * 32 + l4 * 8);
    float4 bb0 = b4[0], bb1 = b4[1];
    float o[8];
    o[0] = fmaxf(a[0] * di + bb0.x, 0.f);
    o[1] = fmaxf(a[1] * di + bb0.y, 0.f);
    o[2] = fmaxf(a[2] * di + bb0.z, 0.f);
    o[3] = fmaxf(a[3] * di + bb0.w, 0.f);
    o[4] = fmaxf(a[4] * di + bb1.x, 0.f);
    o[5] = fmaxf(a[5] * di + bb1.y, 0.f);
    o[6] = fmaxf(a[6] * di + bb1.z, 0.f);
    o[7] = fmaxf(a[7] * di + bb1.w, 0.f);

    ushort hs[8];
#pragma unroll
    for (int i = 0; i < 8; ++i) hs[i] = f2bf(o[i]);
    u32x4 hv;
    hv.x = (uint)hs[0] | ((uint)hs[1] << 16);
    hv.y = (uint)hs[2] | ((uint)hs[3] << 16);
    hv.z = (uint)hs[4] | ((uint)hs[5] << 16);
    hv.w = (uint)hs[6] | ((uint)hs[7] << 16);
    __builtin_nontemporal_store(hv, (u32x4*)(X + (size_t)c * XS + (size_t)node * 32 + l4 * 8));
}

// ---------------- pool + node head (no atomics), 16 partials/graph ----------------
__global__ __launch_bounds__(256) void k_pool(const ushort* __restrict__ X,
                                              const int* __restrict__ gstart,
                                              const float* __restrict__ nw,
                                              const float* __restrict__ nbp,
                                              float* __restrict__ out_node,
                                              float* __restrict__ psum_part) {
    int g = blockIdx.x >> 4, p = blockIdx.x & 15;
    int s = gstart[g], e = gstart[g + 1];
    int len = e - s;
    int lp = (len + 15) >> 4;
    int ps = s + p * lp, pe = min(ps + lp, e);
    int q = threadIdx.x >> 6, lane = threadIdx.x & 63;
    const uint* hb = (const uint*)X + (size_t)(lane >> 4) * (XS / 2) + (lane & 15);
    float2 w = ((const float2*)nw)[lane];
    float nbv = nbp[0];
    float2 acc = {0.f, 0.f};
    for (int node = ps + q; node < pe; node += 4) {
        uint hv = hb[(size_t)node * 16];
        float2 v;
        v.x = bf2f((ushort)hv);
        v.y = bf2f((ushort)(hv >> 16));
        acc.x += v.x; acc.y += v.y;
        float dot = v.x * w.x + v.y * w.y;
#pragma unroll
        for (int off = 32; off; off >>= 1) dot += __shfl_down(dot, off);
        if (lane == 0) out_node[node] = dot + nbv;
    }
    __shared__ float lds[4 * FEA];
    lds[q * FEA + lane * 2 + 0] = acc.x;
    lds[q * FEA + lane * 2 + 1] = acc.y;
    __syncthreads();
    if (threadIdx.x < FEA) {
        psum_part[(size_t)blockIdx.x * FEA + threadIdx.x] =
            lds[threadIdx.x] + lds[FEA + threadIdx.x] +
            lds[2 * FEA + threadIdx.x] + lds[3 * FEA + threadIdx.x];
    }
}

// ---------------- MLP layer 1 (direct strided w1 reads) ----------------
__global__ __launch_bounds__(256) void k_mlp1(const float* __restrict__ psum_part,
                                              const int* __restrict__ gstart,
                                              const float* __restrict__ w1,
                                              const float* __restrict__ b1,
                                              float* __restrict__ h1ws) {
    __shared__ float feas[NG * 132];   // pad 132 to spread banks
    for (int idx = threadIdx.x; idx < NG * FEA; idx += 256) {
        int g = idx >> 7, f = idx & 127;
        const float* pp = psum_part + (size_t)g * 16 * FEA + f;
        float sum = 0.f;
#pragma unroll
        for (int p = 0; p < 16; ++p) sum += pp[p * FEA];
        float cnt = fmaxf((float)(gstart[g + 1] - gstart[g]), 1.0f);
        feas[g * 132 + f] = sum / cnt;
    }
    __syncthreads();
    int g = threadIdx.x >> 2, jj = threadIdx.x & 3;
    int j = blockIdx.x * 4 + jj;
    const float* fr = feas + g * 132;
    float a0 = 0.f, a1 = 0.f, a2 = 0.f, a3 = 0.f;
#pragma unroll 8
    for (int k = 0; k < FEA; k += 4) {
        a0 += fr[k + 0] * w1[(k + 0) * AH + j];
        a1 += fr[k + 1] * w1[(k + 1) * AH + j];
        a2 += fr[k + 2] * w1[(k + 2) * AH + j];
        a3 += fr[k + 3] * w1[(k + 3) * AH + j];
    }
    h1ws[(size_t)g * AH + j] = fmaxf((a0 + a1) + (a2 + a3) + b1[j], 0.f);
}

// ---------------- MLP layer 2 (direct strided w2 reads) ----------------
__global__ __launch_bounds__(256) void k_mlp2(const float* __restrict__ h1ws,
                                              const float* __restrict__ w2,
                                              const float* __restrict__ b2,
                                              float* __restrict__ out_fea) {
    int f = blockIdx.x;
    int g = threadIdx.x >> 2, q = threadIdx.x & 3;
    const float* hr = h1ws + (size_t)g * AH + q * 128;
    const float* wr = w2 + (size_t)q * 128 * FEA + f;
    float a0 = 0.f, a1 = 0.f, a2 = 0.f, a3 = 0.f;
#pragma unroll 8
    for (int k = 0; k < 128; k += 4) {
        a0 += hr[k + 0] * wr[(k + 0) * FEA];
        a1 += hr[k + 1] * wr[(k + 1) * FEA];
        a2 += hr[k + 2] * wr[(k + 2) * FEA];
        a3 += hr[k + 3] * wr[(k + 3) * FEA];
    }
    float p = (a0 + a1) + (a2 + a3);
    p += __shfl_xor(p, 1);
    p += __shfl_xor(p, 2);
    if (q == 0) out_fea[(size_t)g * FEA + f] = p + b2[f];
}

extern "C" void kernel_launch(void* const* d_in, const int* in_sizes, int n_in,
                              void* d_out, int out_size, void* d_ws, size_t ws_size,
                              hipStream_t stream) {
    const float* x     = (const float*)d_in[0];
    const int*   ei    = (const int*)d_in[1];
    const int*   batch = (const int*)d_in[2];
    const float* convW = (const float*)d_in[3];
    const float* convb = (const float*)d_in[4];
    const float* w1    = (const float*)d_in[5];
    const float* b1    = (const float*)d_in[6];
    const float* w2    = (const float*)d_in[7];
    const float* b2    = (const float*)d_in[8];
    const float* nw    = (const float*)d_in[9];
    const float* nb    = (const float*)d_in[10];
    float* out = (float*)d_out;

    // workspace layout (4-byte word offsets)
    char* wsb = (char*)d_ws;
    int*    deg    = (int*)wsb;                        // 50000
    float*  dinv   = (float*)(wsb + 50048ll * 4);      // 50000
    int*    rowptr = (int*)(wsb + 100096ll * 4);       // 50001 (local)
    int*    rowg   = (int*)(wsb + 150160ll * 4);       // 50001 (global/final)
    int*    bsum   = (int*)(wsb + 200224ll * 4);       // 196
    int*    boff   = (int*)(wsb + 200424ll * 4);       // 196
    int*    gstart = (int*)(wsb + 200624ll * 4);       // 65
    int*    rankw  = (int*)(wsb + 200704ll * 4);       // 400000 words
    ushort* rank   = (ushort*)rankw;                   // 800000 ushort
    float*  h1ws   = (float*)rankw;                    // 32768 w (after fill)
    ushort* eidx   = (ushort*)(wsb + 950656ll * 4);    // <=1.3M ushort
    ushort* H      = (ushort*)(wsb + 1600672ll * 4);   // 4*(N+1)*32 bf16
    ushort* X      = (ushort*)(wsb + 4800736ll * 4);   // 4*N*32 bf16
    float*  psum_part = (float*)(wsb + 8000736ll * 4); // 1024*128 floats

    const int* srcp = ei;
    const int* dstp = ei + N_EDGES;

    // ---- CSR build overlapped with gemm layer 0 ----
    hipMemsetAsync(deg, 0, N_NODES * sizeof(int), stream);
    k_mega<<<MGRID, 256, 0, stream>>>(dstp, deg, rank, x, convW, H);
    k_scan1<<<NBLK, 256, 0, stream>>>(deg, rowptr, bsum, dinv);
    k_scan2<<<1 + (HU4 + 255) / 256, 256, 0, stream>>>(bsum, boff, rowg, dinv, H);
    k_fill2<<<FC, 256, 0, stream>>>(srcp, dstp, rowptr, boff, rank, deg, batch,
                                    eidx, rowg, gstart);

    // ---- GCN layers ----
    k_gather<<<GNB * 4, 256, 0, stream>>>(rowg, eidx, dinv, H, convb, X);
    for (int l = 1; l < NL; ++l) {
        k_gemm<<<1024, 256, 0, stream>>>(X, convW + (size_t)l * FEA * FEA, dinv, H);
        k_gather<<<GNB * 4, 256, 0, stream>>>(
            rowg, eidx, dinv, H, convb + (size_t)l * FEA, X);
    }

    // ---- heads ----
    k_pool<<<NG * 16, 256, 0, stream>>>(X, gstart, nw, nb, out, psum_part);
    k_mlp1<<<128, 256, 0, stream>>>(psum_part, gstart, w1, b1, h1ws);
    k_mlp2<<<128, 256, 0, stream>>>(h1ws, w2, b2, out + N_NODES);
}

// Round 21
// 213.206 us; speedup vs baseline: 1.0542x; 1.0323x over previous
//
#include <hip/hip_runtime.h>

#define N_NODES 50000
#define N_EDGES 800000
#define FEA 128
#define NL 3
#define AH 512
#define NG 64
#define NBLK 196   // ceil(50000/256)

typedef short bf16x8 __attribute__((ext_vector_type(8)));
typedef float f32x4 __attribute__((ext_vector_type(4)));
typedef uint  u32x4 __attribute__((ext_vector_type(4)));

__device__ __forceinline__ ushort f2bf(float f) {   // RTN-even
    uint u = __float_as_uint(f);
    uint r = u + 0x7FFFu + ((u >> 16) & 1u);
    return (ushort)(r >> 16);
}
__device__ __forceinline__ float bf2f(ushort u) {
    return __uint_as_float((uint)u << 16);
}

// Column-sliced layouts: 4 slices of 64B (32 bf16 features) per row.
#define HS ((size_t)(N_NODES + 1) * 32)   // ushorts per H slice
#define XS ((size_t)N_NODES * 32)   // ushorts per X slice

// ---------------- mega: persistent hist (640 blocks x 1250 edges) || gemm0 ----------------
// period-21 role map: 5 hist + 16 gemm per period, 128 periods.
#define EPB 1250
#define PER 21
#define MGRID (PER * 128 + 1)   // 2689 incl pad-row block
__global__ __launch_bounds__(256) void k_mega(const int* __restrict__ dst,
                                              int* __restrict__ deg,
                                              ushort* __restrict__ rank,
                                              const float* __restrict__ x,
                                              const float* __restrict__ convW0,
                                              ushort* __restrict__ H) {
    int blk = blockIdx.x;
    if (blk == MGRID - 1) {                // zero H pad rows (4 slices x 64B)
        if (threadIdx.x < 64) {
            int c = threadIdx.x >> 4, j = threadIdx.x & 15;
            ((uint*)H)[(size_t)c * (HS / 2) + (size_t)N_NODES * 16 + j] = 0;
        }
        return;
    }
    int p = blk / PER, r = blk - p * PER;
    if (r < 5) {                           // persistent histogram role
        int hid = p * 5 + r;               // 0..639
        int base = hid * EPB;
        int end = base + EPB;
        for (int e = base + threadIdx.x; e < end; e += 256)
            rank[e] = (ushort)atomicAdd(&deg[dst[e]], 1);
        return;
    }
    // gemm0 role: col-half gid, 1 col-tile (16 cols) per wave
    int gid = p * 16 + (r - 5);            // 0..2047
    const int colhalf = gid & 1;
    const int rstart = gid >> 1;           // 0..1023
    const int wv = threadIdx.x >> 6;
    const int lane = threadIdx.x & 63;
    const int lr = lane & 15;
    const int lk = lane >> 4;

    const int col = colhalf * 64 + wv * 16 + lr;
    bf16x8 bhi[4], blo[4];
#pragma unroll
    for (int kf = 0; kf < 4; ++kf) {
#pragma unroll
        for (int j = 0; j < 8; ++j) {
            float w = convW0[(size_t)(kf * 32 + lk * 8 + j) * FEA + col];
            ushort h = f2bf(w);
            bhi[kf][j] = (short)h;
            blo[kf][j] = (short)f2bf(w - bf2f(h));
        }
    }
    const int slice = colhalf * 2 + (wv >> 1);
    const int intra = (wv & 1) * 16 + lr;

    for (int rt = rstart; rt < N_NODES / 16; rt += 1024) {
        int r0 = rt * 16;
        const float* xrow = x + (size_t)(r0 + lr) * FEA;
        bf16x8 a[4];
#pragma unroll
        for (int kf = 0; kf < 4; ++kf) {
            float4 u0 = *(const float4*)(xrow + kf * 32 + lk * 8);
            float4 u1 = *(const float4*)(xrow + kf * 32 + lk * 8 + 4);
            a[kf][0] = (short)f2bf(u0.x); a[kf][1] = (short)f2bf(u0.y);
            a[kf][2] = (short)f2bf(u0.z); a[kf][3] = (short)f2bf(u0.w);
            a[kf][4] = (short)f2bf(u1.x); a[kf][5] = (short)f2bf(u1.y);
            a[kf][6] = (short)f2bf(u1.z); a[kf][7] = (short)f2bf(u1.w);
        }
        f32x4 acc = {0.f, 0.f, 0.f, 0.f};
#pragma unroll
        for (int kf = 0; kf < 4; ++kf) {
            acc = __builtin_amdgcn_mfma_f32_16x16x32_bf16(a[kf], bhi[kf], acc, 0, 0, 0);
            acc = __builtin_amdgcn_mfma_f32_16x16x32_bf16(a[kf], blo[kf], acc, 0, 0, 0);
        }
        // store UNSCALED (dinv applied later by hscale in k_scan2)
#pragma unroll
        for (int reg = 0; reg < 4; ++reg) {
            int orow = r0 + lk * 4 + reg;
            H[(size_t)slice * HS + (size_t)orow * 32 + intra] = f2bf(acc[reg]);
        }
    }
}

// ---------------- scan helpers ----------------
__device__ __forceinline__ int block_scan_incl(int v, int* wsum) {
    int lane = threadIdx.x & 63, w = threadIdx.x >> 6;
    int s = v;
#pragma unroll
    for (int off = 1; off < 64; off <<= 1) {
        int t = __shfl_up(s, off);
        if (lane >= off) s += t;
    }
    if (lane == 63) wsum[w] = s;
    __syncthreads();
    int woff = 0;
    for (int k = 0; k < w; ++k) woff += wsum[k];
    return woff + s;  // block-wide inclusive
}

__global__ __launch_bounds__(256) void k_scan1(const int* __restrict__ deg,
                                               int* __restrict__ rowptr,
                                               int* __restrict__ bsum,
                                               float* __restrict__ dinv) {
    __shared__ int wsum[4];
    int i = blockIdx.x * 256 + threadIdx.x;
    int v = (i < N_NODES) ? deg[i] : 0;
    int pv = (v + 7) & ~7;                       // pad to multiple of 8
    int incl = block_scan_incl(pv, wsum);
    if (i < N_NODES) {
        rowptr[i] = incl - pv;                   // local exclusive
        dinv[i] = rsqrtf((float)v + 1.0f);
    }
    if (threadIdx.x == 255) bsum[blockIdx.x] = incl;
}

// scan2: block-sum scan (1 block)  ||  hscale: H *= dinv rowwise (3126 blocks)
#define HU4 (4 * (N_NODES + 1) * 4)   // 800016 uint4 elements in H
__global__ __launch_bounds__(256) void k_scan2(int* __restrict__ bsum,
                                               int* __restrict__ boff,
                                               int* __restrict__ rowg,
                                               const float* __restrict__ dinv,
                                               ushort* __restrict__ H) {
    if (blockIdx.x == 0) {
        __shared__ int wsum[4];
        int v = (threadIdx.x < NBLK) ? bsum[threadIdx.x] : 0;
        int incl = block_scan_incl(v, wsum);
        if (threadIdx.x < NBLK) boff[threadIdx.x] = incl - v;
        if (threadIdx.x == NBLK - 1) rowg[N_NODES] = incl;  // total padded edges
        return;
    }
    int i = (blockIdx.x - 1) * 256 + threadIdx.x;
    if (i >= HU4) return;
    int c = i / ((N_NODES + 1) * 4);
    int rem = i - c * ((N_NODES + 1) * 4);
    int row = rem >> 2;
    if (row >= N_NODES) return;                  // pad row stays zero
    float dd = dinv[row];
    u32x4 v = ((u32x4*)H)[i];
    uint w;
    w = v.x; v.x = (uint)f2bf(bf2f((ushort)w) * dd) | ((uint)f2bf(bf2f((ushort)(w >> 16)) * dd) << 16);
    w = v.y; v.y = (uint)f2bf(bf2f((ushort)w) * dd) | ((uint)f2bf(bf2f((ushort)(w >> 16)) * dd) << 16);
    w = v.z; v.z = (uint)f2bf(bf2f((ushort)w) * dd) | ((uint)f2bf(bf2f((ushort)(w >> 16)) * dd) << 16);
    w = v.w; v.w = (uint)f2bf(bf2f((ushort)w) * dd) | ((uint)f2bf(bf2f((ushort)(w >> 16)) * dd) << 16);
    ((u32x4*)H)[i] = v;
}

// ---------------- fused: CSR fill | pad slots + final rowptr (rowg) | graph bounds ----------------
#define FA 3125
#define FB (FA + NBLK)
#define FC (FB + NBLK)
__global__ __launch_bounds__(256) void k_fill2(const int* __restrict__ src,
                                               const int* __restrict__ dst,
                                               const int* __restrict__ rowptr,
                                               const int* __restrict__ boff,
                                               const ushort* __restrict__ rank,
                                               const int* __restrict__ deg,
                                               const int* __restrict__ batch,
                                               ushort* __restrict__ eidx,
                                               int* __restrict__ rowg,
                                               int* __restrict__ gstart) {
    int blk = blockIdx.x;
    if (blk < FA) {                        // CSR fill (no atomics); global base inline
        int e = blk * 256 + threadIdx.x;
        int d = dst[e];
        int base = rowptr[d] + boff[d >> 8];
        eidx[base + (int)rank[e]] = (ushort)src[e];
    } else if (blk < FB) {                 // pad slots + write final rowptr copy
        int i = (blk - FA) * 256 + threadIdx.x;
        if (i < N_NODES) {
            int d = deg[i];
            int r = rowptr[i] + boff[i >> 8];
            rowg[i] = r;
            int pd = (d + 7) & ~7;
            for (int k = d; k < pd; ++k) eidx[r + k] = (ushort)N_NODES;
        }
    } else {                               // graph bounds from sorted batch
        int i = (blk - FB) * 256 + threadIdx.x;
        if (i < N_NODES) {
            int b = batch[i];
            int bp = (i == 0) ? -1 : batch[i - 1];
            for (int g = bp + 1; g <= b; ++g) gstart[g] = i;
            if (i == N_NODES - 1)
                for (int g = b + 1; g <= NG; ++g) gstart[g] = N_NODES;
        }
    }
}

// ---------------- MFMA GEMM (layers 1,2): H'cs = dinv * (Xcs @ W), W split in-register ----------------
__global__ __launch_bounds__(256) void k_gemm(const ushort* __restrict__ X,
                                              const float* __restrict__ convWl,
                                              const float* __restrict__ dinv,
                                              ushort* __restrict__ H) {
    const int wv = threadIdx.x >> 6;
    const int lane = threadIdx.x & 63;
    const int lr = lane & 15;
    const int lk = lane >> 4;

    bf16x8 bhi[2][4], blo[2][4];
#pragma unroll
    for (int ct = 0; ct < 2; ++ct) {
        int col = wv * 32 + ct * 16 + lr;
#pragma unroll
        for (int kf = 0; kf < 4; ++kf) {
#pragma unroll
            for (int j = 0; j < 8; ++j) {
                float w = convWl[(size_t)(kf * 32 + lk * 8 + j) * FEA + col];
                ushort h = f2bf(w);
                bhi[ct][kf][j] = (short)h;
                blo[ct][kf][j] = (short)f2bf(w - bf2f(h));
            }
        }
    }

    for (int rt = blockIdx.x; rt < N_NODES / 16; rt += gridDim.x) {
        int r0 = rt * 16;
        bf16x8 a[4];
#pragma unroll
        for (int kf = 0; kf < 4; ++kf) {
            a[kf] = *(const bf16x8*)(X + (size_t)kf * XS + (size_t)(r0 + lr) * 32 + lk * 8);
        }
        f32x4 acc0 = {0.f, 0.f, 0.f, 0.f};
        f32x4 acc1 = {0.f, 0.f, 0.f, 0.f};
#pragma unroll
        for (int kf = 0; kf < 4; ++kf) {
            acc0 = __builtin_amdgcn_mfma_f32_16x16x32_bf16(a[kf], bhi[0][kf], acc0, 0, 0, 0);
            acc0 = __builtin_amdgcn_mfma_f32_16x16x32_bf16(a[kf], blo[0][kf], acc0, 0, 0, 0);
            acc1 = __builtin_amdgcn_mfma_f32_16x16x32_bf16(a[kf], bhi[1][kf], acc1, 0, 0, 0);
            acc1 = __builtin_amdgcn_mfma_f32_16x16x32_bf16(a[kf], blo[1][kf], acc1, 0, 0, 0);
        }
#pragma unroll
        for (int reg = 0; reg < 4; ++reg) {
            int orow = r0 + lk * 4 + reg;
            float s = dinv[orow];
            H[(size_t)wv * HS + (size_t)orow * 32 + lr]      = f2bf(acc0[reg] * s);
            H[(size_t)wv * HS + (size_t)orow * 32 + 16 + lr] = f2bf(acc1[reg] * s);
        }
    }
}

// ---------------- gather: 4 lanes/node x one 64B slice; 16-edge MLP batches ----------------
#define GNPB 64    // nodes per block
#define GNB ((N_NODES + GNPB - 1) / GNPB)
__global__ __launch_bounds__(256) void k_gather(const int* __restrict__ rowg,
                                                const ushort* __restrict__ eidx,
                                                const float* __restrict__ dinv,
                                                const ushort* __restrict__ H,
                                                const float* __restrict__ b,
                                                ushort* __restrict__ X) {
    int c = blockIdx.x & 3;
    int node = (blockIdx.x >> 2) * GNPB + (threadIdx.x >> 2);
    int l4 = threadIdx.x & 3;              // uint4 offset within 64B slice row
    if (node >= N_NODES) return;
    const uint4* Hs = (const uint4*)H + (size_t)c * (N_NODES + 1) * 4;
    int r0 = rowg[node], r1 = rowg[node + 1];

    float a[8] = {0.f, 0.f, 0.f, 0.f, 0.f, 0.f, 0.f, 0.f};
#define ACC8(u)                                                              \
    do {                                                                     \
        a[0] += __uint_as_float((u).x << 16);                                \
        a[1] += __uint_as_float((u).x & 0xffff0000u);                        \
        a[2] += __uint_as_float((u).y << 16);                                \
        a[3] += __uint_as_float((u).y & 0xffff0000u);                        \
        a[4] += __uint_as_float((u).z << 16);                                \
        a[5] += __uint_as_float((u).z & 0xffff0000u);                        \
        a[6] += __uint_as_float((u).w << 16);                                \
        a[7] += __uint_as_float((u).w & 0xffff0000u);                        \
    } while (0)

    uint4 sv = Hs[(size_t)node * 4 + l4];  // self term
    ACC8(sv);

    int j = r0;
    for (; j + 16 <= r1; j += 16) {        // 16 independent H-row loads in flight
        uint4 ev0 = *(const uint4*)(eidx + j);
        uint4 ev1 = *(const uint4*)(eidx + j + 8);
        uint4 h0 = Hs[(size_t)(ev0.x & 0xffff) * 4 + l4];
        uint4 h1 = Hs[(size_t)(ev0.x >> 16) * 4 + l4];
        uint4 h2 = Hs[(size_t)(ev0.y & 0xffff) * 4 + l4];
        uint4 h3 = Hs[(size_t)(ev0.y >> 16) * 4 + l4];
        uint4 h4 = Hs[(size_t)(ev0.z & 0xffff) * 4 + l4];
        uint4 h5 = Hs[(size_t)(ev0.z >> 16) * 4 + l4];
        uint4 h6 = Hs[(size_t)(ev0.w & 0xffff) * 4 + l4];
        uint4 h7 = Hs[(size_t)(ev0.w >> 16) * 4 + l4];
        uint4 g0 = Hs[(size_t)(ev1.x & 0xffff) * 4 + l4];
        uint4 g1 = Hs[(size_t)(ev1.x >> 16) * 4 + l4];
        uint4 g2 = Hs[(size_t)(ev1.y & 0xffff) * 4 + l4];
        uint4 g3 = Hs[(size_t)(ev1.y >> 16) * 4 + l4];
        uint4 g4 = Hs[(size_t)(ev1.z & 0xffff) * 4 + l4];
        uint4 g5 = Hs[(size_t)(ev1.z >> 16) * 4 + l4];
        uint4 g6 = Hs[(size_t)(ev1.w & 0xffff) * 4 + l4];
        uint4 g7 = Hs[(size_t)(ev1.w >> 16) * 4 + l4];
        ACC8(h0); ACC8(h1); ACC8(h2); ACC8(h3);
        ACC8(h4); ACC8(h5); ACC8(h6); ACC8(h7);
        ACC8(g0); ACC8(g1); ACC8(g2); ACC8(g3);
        ACC8(g4); ACC8(g5); ACC8(g6); ACC8(g7);
    }
    if (j < r1) {                          // 8-edge tail
        uint4 ev = *(const uint4*)(eidx + j);
        uint4 h0 = Hs[(size_t)(ev.x & 0xffff) * 4 + l4];
        uint4 h1 = Hs[(size_t)(ev.x >> 16) * 4 + l4];
        uint4 h2 = Hs[(size_t)(ev.y & 0xffff) * 4 + l4];
        uint4 h3 = Hs[(size_t)(ev.y >> 16) * 4 + l4];
        uint4 h4 = Hs[(size_t)(ev.z & 0xffff) * 4 + l4];
        uint4 h5 = Hs[(size_t)(ev.z >> 16) * 4 + l4];
        uint4 h6 = Hs[(size_t)(ev.w & 0xffff) * 4 + l4];
        uint4 h7 = Hs[(size_t)(ev.w >> 16) * 4 + l4];
        ACC8(h0); ACC8(h1); ACC8(h2); ACC8(h3);
        ACC8(h4); ACC8(h5); ACC8(h6); ACC8(h7);
    }
#undef ACC8

    float di = dinv[node];
    const float4* b4 = (const float4*)(b + c * 32 + l4 * 8);
    float4 bb0 = b4[0], bb1 = b4[1];
    float o[8];
    o[0] = fmaxf(a[0] * di + bb0.x, 0.f);
    o[1] = fmaxf(a[1] * di + bb0.y, 0.f);
    o[2] = fmaxf(a[2] * di + bb0.z, 0.f);
    o[3] = fmaxf(a[3] * di + bb0.w, 0.f);
    o[4] = fmaxf(a[4] * di + bb1.x, 0.f);
    o[5] = fmaxf(a[5] * di + bb1.y, 0.f);
    o[6] = fmaxf(a[6] * di + bb1.z, 0.f);
    o[7] = fmaxf(a[7] * di + bb1.w, 0.f);

    ushort hs[8];
#pragma unroll
    for (int i = 0; i < 8; ++i) hs[i] = f2bf(o[i]);
    u32x4 hv;
    hv.x = (uint)hs[0] | ((uint)hs[1] << 16);
    hv.y = (uint)hs[2] | ((uint)hs[3] << 16);
    hv.z = (uint)hs[4] | ((uint)hs[5] << 16);
    hv.w = (uint)hs[6] | ((uint)hs[7] << 16);
    __builtin_nontemporal_store(hv, (u32x4*)(X + (size_t)c * XS + (size_t)node * 32 + l4 * 8));
}

// ---------------- pool + node head (no atomics), 16 partials/graph ----------------
__global__ __launch_bounds__(256) void k_pool(const ushort* __restrict__ X,
                                              const int* __restrict__ gstart,
                                              const float* __restrict__ nw,
                                              const float* __restrict__ nbp,
                                              float* __restrict__ out_node,
                                              float* __restrict__ psum_part) {
    int g = blockIdx.x >> 4, p = blockIdx.x & 15;
    int s = gstart[g], e = gstart[g + 1];
    int len = e - s;
    int lp = (len + 15) >> 4;
    int ps = s + p * lp, pe = min(ps + lp, e);
    int q = threadIdx.x >> 6, lane = threadIdx.x & 63;
    const uint* hb = (const uint*)X + (size_t)(lane >> 4) * (XS / 2) + (lane & 15);
    float2 w = ((const float2*)nw)[lane];
    float nbv = nbp[0];
    float2 acc = {0.f, 0.f};
    for (int node = ps + q; node < pe; node += 4) {
        uint hv = hb[(size_t)node * 16];
        float2 v;
        v.x = bf2f((ushort)hv);
        v.y = bf2f((ushort)(hv >> 16));
        acc.x += v.x; acc.y += v.y;
        float dot = v.x * w.x + v.y * w.y;
#pragma unroll
        for (int off = 32; off; off >>= 1) dot += __shfl_down(dot, off);
        if (lane == 0) out_node[node] = dot + nbv;
    }
    __shared__ float lds[4 * FEA];
    lds[q * FEA + lane * 2 + 0] = acc.x;
    lds[q * FEA + lane * 2 + 1] = acc.y;
    __syncthreads();
    if (threadIdx.x < FEA) {
        psum_part[(size_t)blockIdx.x * FEA + threadIdx.x] =
            lds[threadIdx.x] + lds[FEA + threadIdx.x] +
            lds[2 * FEA + threadIdx.x] + lds[3 * FEA + threadIdx.x];
    }
}

// ---------------- MLP layer 1 (direct strided w1 reads) ----------------
__global__ __launch_bounds__(256) void k_mlp1(const float* __restrict__ psum_part,
                                              const int* __restrict__ gstart,
                                              const float* __restrict__ w1,
                                              const float* __restrict__ b1,
                                              float* __restrict__ h1ws) {
    __shared__ float feas[NG * 132];   // pad 132 to spread banks
    for (int idx = threadIdx.x; idx < NG * FEA; idx += 256) {
        int g = idx >> 7, f = idx & 127;
        const float* pp = psum_part + (size_t)g * 16 * FEA + f;
        float sum = 0.f;
#pragma unroll
        for (int p = 0; p < 16; ++p) sum += pp[p * FEA];
        float cnt = fmaxf((float)(gstart[g + 1] - gstart[g]), 1.0f);
        feas[g * 132 + f] = sum / cnt;
    }
    __syncthreads();
    int g = threadIdx.x >> 2, jj = threadIdx.x & 3;
    int j = blockIdx.x * 4 + jj;
    const float* fr = feas + g * 132;
    float a0 = 0.f, a1 = 0.f, a2 = 0.f, a3 = 0.f;
#pragma unroll 8
    for (int k = 0; k < FEA; k += 4) {
        a0 += fr[k + 0] * w1[(k + 0) * AH + j];
        a1 += fr[k + 1] * w1[(k + 1) * AH + j];
        a2 += fr[k + 2] * w1[(k + 2) * AH + j];
        a3 += fr[k + 3] * w1[(k + 3) * AH + j];
    }
    h1ws[(size_t)g * AH + j] = fmaxf((a0 + a1) + (a2 + a3) + b1[j], 0.f);
}

// ---------------- MLP layer 2 (direct strided w2 reads) ----------------
__global__ __launch_bounds__(256) void k_mlp2(const float* __restrict__ h1ws,
                                              const float* __restrict__ w2,
                                              const float* __restrict__ b2,
                                              float* __restrict__ out_fea) {
    int f = blockIdx.x;
    int g = threadIdx.x >> 2, q = threadIdx.x & 3;
    const float* hr = h1ws + (size_t)g * AH + q * 128;
    const float* wr = w2 + (size_t)q * 128 * FEA + f;
    float a0 = 0.f, a1 = 0.f, a2 = 0.f, a3 = 0.f;
#pragma unroll 8
    for (int k = 0; k < 128; k += 4) {
        a0 += hr[k + 0] * wr[(k + 0) * FEA];
        a1 += hr[k + 1] * wr[(k + 1) * FEA];
        a2 += hr[k + 2] * wr[(k + 2) * FEA];
        a3 += hr[k + 3] * wr[(k + 3) * FEA];
    }
    float p = (a0 + a1) + (a2 + a3);
    p += __shfl_xor(p, 1);
    p += __shfl_xor(p, 2);
    if (q == 0) out_fea[(size_t)g * FEA + f] = p + b2[f];
}

extern "C" void kernel_launch(void* const* d_in, const int* in_sizes, int n_in,
                              void* d_out, int out_size, void* d_ws, size_t ws_size,
                              hipStream_t stream) {
    const float* x     = (const float*)d_in[0];
    const int*   ei    = (const int*)d_in[1];
    const int*   batch = (const int*)d_in[2];
    const float* convW = (const float*)d_in[3];
    const float* convb = (const float*)d_in[4];
    const float* w1    = (const float*)d_in[5];
    const float* b1    = (const float*)d_in[6];
    const float* w2    = (const float*)d_in[7];
    const float* b2    = (const float*)d_in[8];
    const float* nw    = (const float*)d_in[9];
    const float* nb    = (const float*)d_in[10];
    float* out = (float*)d_out;

    // workspace layout (4-byte word offsets)
    char* wsb = (char*)d_ws;
    int*    deg    = (int*)wsb;                        // 50000
    float*  dinv   = (float*)(wsb + 50048ll * 4);      // 50000
    int*    rowptr = (int*)(wsb + 100096ll * 4);       // 50001 (local)
    int*    rowg   = (int*)(wsb + 150160ll * 4);       // 50001 (global/final)
    int*    bsum   = (int*)(wsb + 200224ll * 4);       // 196
    int*    boff   = (int*)(wsb + 200424ll * 4);       // 196
    int*    gstart = (int*)(wsb + 200624ll * 4);       // 65
    int*    rankw  = (int*)(wsb + 200704ll * 4);       // 400000 words
    ushort* rank   = (ushort*)rankw;                   // 800000 ushort
    float*  h1ws   = (float*)rankw;                    // 32768 w (after fill)
    ushort* eidx   = (ushort*)(wsb + 950656ll * 4);    // <=1.3M ushort
    ushort* H      = (ushort*)(wsb + 1600672ll * 4);   // 4*(N+1)*32 bf16
    ushort* X      = (ushort*)(wsb + 4800736ll * 4);   // 4*N*32 bf16
    float*  psum_part = (float*)(wsb + 8000736ll * 4); // 1024*128 floats

    const int* srcp = ei;
    const int* dstp = ei + N_EDGES;

    // ---- CSR build overlapped with gemm layer 0 ----
    hipMemsetAsync(deg, 0, N_NODES * sizeof(int), stream);
    k_mega<<<MGRID, 256, 0, stream>>>(dstp, deg, rank, x, convW, H);
    k_scan1<<<NBLK, 256, 0, stream>>>(deg, rowptr, bsum, dinv);
    k_scan2<<<1 + (HU4 + 255) / 256, 256, 0, stream>>>(bsum, boff, rowg, dinv, H);
    k_fill2<<<FC, 256, 0, stream>>>(srcp, dstp, rowptr, boff, rank, deg, batch,
                                    eidx, rowg, gstart);

    // ---- GCN layers ----
    k_gather<<<GNB * 4, 256, 0, stream>>>(rowg, eidx, dinv, H, convb, X);
    for (int l = 1; l < NL; ++l) {
        k_gemm<<<1024, 256, 0, stream>>>(X, convW + (size_t)l * FEA * FEA, dinv, H);
        k_gather<<<GNB * 4, 256, 0, stream>>>(
            rowg, eidx, dinv, H, convb + (size_t)l * FEA, X);
    }

    // ---- heads ----
    k_pool<<<NG * 16, 256, 0, stream>>>(X, gstart, nw, nb, out, psum_part);
    k_mlp1<<<128, 256, 0, stream>>>(psum_part, gstart, w1, b1, h1ws);
    k_mlp2<<<128, 256, 0, stream>>>(h1ws, w2, b2, out + N_NODES);
}